// Round 1
// baseline (392.793 us; speedup 1.0000x reference)
//
#include <hip/hip_runtime.h>
#include <stdint.h>
#include <math.h>

// FuXi block on MI355X, round 10: barrier-free attention.
// r9 post-mortem: attn VALUBusy 57% + MfmaUtil 16% + Occupancy 18.7% -> ~27% of
// cycles neither pipe issues. Cause: 2 __syncthreads per K/V tile (each drains
// vmcnt/lgkmcnt) with only 2 blocks/CU (59 KB LDS) => lockstep phases, no overlap.
// Fix: drop Ks/Vs LDS staging entirely -- K and V MFMA fragments are 16B-contiguous
// global slices (L1 serves the 4-wave intra-block reuse, L2 the 16-block (b,h) reuse).
// Pl is wave-private => NO barriers in the t-loop at all. LDS 59.4->26.4 KB.
// XCD-chunk swizzle keeps each (b,h)'s 16 blocks on one XCD (K/V L2-resident, 1MB/XCD).

#define D    1024
#define NH   16
#define DH   64
#define B_   2
#define S_   2048
#define ROWS 4096
#define LQ   4096          // QKVU row stride
#define EPSR 1e-8f

typedef unsigned short u16;
typedef __attribute__((ext_vector_type(8))) short short8;
typedef __attribute__((ext_vector_type(4))) float f32x4;

__device__ __forceinline__ float bf2f(u16 u) {
    union { uint32_t i; float f; } c; c.i = ((uint32_t)u) << 16; return c.f;
}
__device__ __forceinline__ u16 f2bf(float f) {
    union { float f; uint32_t i; } c; c.f = f;
    uint32_t x = c.i;
    x += 0x7fffu + ((x >> 16) & 1u);
    return (u16)(x >> 16);
}
// pack two f32 -> (bf16(a) | bf16(b)<<16), round-half-up via +0x8000 then v_perm
__device__ __forceinline__ uint32_t pack2bf(float a, float b) {
    union { float f; uint32_t i; } ca, cb; ca.f = a; cb.f = b;
    return __builtin_amdgcn_perm(cb.i + 0x8000u, ca.i + 0x8000u, 0x07060302);
}
#define LOG2E 1.44269504f
// fast silu: one v_exp (=2^x) + one v_rcp, no IEEE divide
__device__ __forceinline__ float silu_fast(float v) {
    return v * __builtin_amdgcn_rcpf(1.0f + __builtin_amdgcn_exp2f(v * -LOG2E));
}

// ---------------- fused weight prep: 7 transposes in one dispatch ----------------
__global__ __launch_bounds__(256) void transpose_all_kernel(
    const float* __restrict__ wq, const float* __restrict__ wk,
    const float* __restrict__ wv, const float* __restrict__ wu,
    const float* __restrict__ w0, const float* __restrict__ w2,
    const float* __restrict__ w1,
    u16* __restrict__ wT4, u16* __restrict__ w0T,
    u16* __restrict__ w2T, u16* __restrict__ w1T)
{
    const unsigned MI = 1u << 20;
    const int z = blockIdx.z;
    const float* W; u16* WT; int N; int noff = 0;
    switch (z) {
        case 0: W = wq; WT = wT4;          N = 1024; break;
        case 1: W = wk; WT = wT4 + 1 * MI; N = 1024; break;
        case 2: W = wv; WT = wT4 + 2 * MI; N = 1024; break;
        case 3: W = wu; WT = wT4 + 3 * MI; N = 1024; break;
        case 4: W = w0; WT = w0T;          N = 1024; break;
        case 5: W = w2; WT = w2T;          N = 1024; break;
        case 6: W = w1; WT = w1T;          N = 2048; noff = 0;    break;
        default:W = w1; WT = w1T;          N = 2048; noff = 1024; break;
    }
    __shared__ float T[64][65];
    const int tid = threadIdx.x;
    const int n0 = (blockIdx.x << 6) + noff;
    const int k0 = blockIdx.y << 6;
    const int rr = tid >> 4;
    const int cc = (tid & 15) << 2;
#pragma unroll
    for (int l = 0; l < 4; ++l) {
        const int r = rr + (l << 4);
        float4 v = *(const float4*)&W[(size_t)(k0 + r) * N + n0 + cc];
        T[cc + 0][r] = v.x; T[cc + 1][r] = v.y;
        T[cc + 2][r] = v.z; T[cc + 3][r] = v.w;
    }
    __syncthreads();
    const int n  = tid >> 2;
    const int ks = (tid & 3) << 4;
#pragma unroll
    for (int m = 0; m < 4; ++m) {
        const int k = ks + (m << 2);
        float4 v = *(const float4*)&T[n][k];
        ushort4 o;
        o.x = f2bf(v.x); o.y = f2bf(v.y); o.z = f2bf(v.z); o.w = f2bf(v.w);
        *(ushort4*)&WT[(size_t)(n0 + n) * 1024 + k0 + k] = o;
    }
}

// ---------------- RMSNorm ----------------
__global__ __launch_bounds__(256) void rmsnorm_kernel(
    const float* __restrict__ inf, const u16* __restrict__ inb, int ldi,
    const float* __restrict__ g,
    const u16* __restrict__ mul, int ldm,
    u16* __restrict__ out, int ldo)
{
    const int row = blockIdx.x;
    const int tid = threadIdx.x;
    const int c = tid << 2;
    float x0, x1, x2, x3;
    if (inb) {
        ushort4 xi = *(const ushort4*)&inb[(size_t)row * ldi + c];
        x0 = bf2f(xi.x); x1 = bf2f(xi.y); x2 = bf2f(xi.z); x3 = bf2f(xi.w);
    } else {
        float4 xi = *(const float4*)&inf[(size_t)row * ldi + c];
        x0 = xi.x; x1 = xi.y; x2 = xi.z; x3 = xi.w;
    }
    float ss = x0*x0 + x1*x1 + x2*x2 + x3*x3;
#pragma unroll
    for (int off = 32; off > 0; off >>= 1) ss += __shfl_down(ss, off, 64);
    __shared__ float red[4];
    if ((tid & 63) == 0) red[tid >> 6] = ss;
    __syncthreads();
    float r = rsqrtf((red[0] + red[1] + red[2] + red[3]) * (1.0f / D) + EPSR);
    float4 gv = *(const float4*)&g[c];
    float v0 = x0 * r * gv.x, v1 = x1 * r * gv.y, v2 = x2 * r * gv.z, v3 = x3 * r * gv.w;
    if (mul) {
        ushort4 mi = *(const ushort4*)&mul[(size_t)row * ldm + c];
        v0 *= bf2f(mi.x); v1 *= bf2f(mi.y); v2 *= bf2f(mi.z); v3 *= bf2f(mi.w);
    }
    ushort4 o;
    o.x = f2bf(v0); o.y = f2bf(v1); o.z = f2bf(v2); o.w = f2bf(v3);
    *(ushort4*)&out[(size_t)row * ldo + c] = o;
}

// ---------------- 128x128 MFMA GEMM (m97 motif), bf16 out ----------------
__global__ __launch_bounds__(256) void gemm128(
    const u16* __restrict__ A, const u16* __restrict__ WT,
    const float* __restrict__ bs0, const float* __restrict__ bs1,
    const float* __restrict__ bs2, const float* __restrict__ bs3,
    u16* __restrict__ outb, int ldo, int actmask,
    u16* __restrict__ VT, int vtsel)
{
    __shared__ u16 As[128 * 32];
    __shared__ u16 Bs[128 * 32];
    const int tid  = threadIdx.x;
    const int wave = tid >> 6;
    const int lane = tid & 63;
    const int lm   = lane & 15;
    const int quad = lane >> 4;
    const int row0 = blockIdx.y << 7;
    const int col0 = blockIdx.x << 7;
    const int wr = (wave >> 1) << 6;
    const int wc = (wave & 1) << 6;

    const int srow = wave * 32 + (lane >> 2);
    const int skp  = (lane & 3) << 3;
    const u16* Ag = A  + (size_t)(row0 + srow) * 1024 + skp;
    const u16* Bg = WT + (size_t)(col0 + srow) * 1024 + skp;
    u16* Asd0 = &As[(wave * 32) * 32];
    u16* Asd1 = &As[(wave * 32 + 16) * 32];
    u16* Bsd0 = &Bs[(wave * 32) * 32];
    u16* Bsd1 = &Bs[(wave * 32 + 16) * 32];

    f32x4 acc[4][4] = {};

    for (int k0 = 0; k0 < 1024; k0 += 32) {
        __syncthreads();
        __builtin_amdgcn_global_load_lds(
            (const __attribute__((address_space(1))) void*)(Ag + k0),
            (__attribute__((address_space(3))) void*)Asd0, 16, 0, 0);
        __builtin_amdgcn_global_load_lds(
            (const __attribute__((address_space(1))) void*)(Ag + 16 * 1024 + k0),
            (__attribute__((address_space(3))) void*)Asd1, 16, 0, 0);
        __builtin_amdgcn_global_load_lds(
            (const __attribute__((address_space(1))) void*)(Bg + k0),
            (__attribute__((address_space(3))) void*)Bsd0, 16, 0, 0);
        __builtin_amdgcn_global_load_lds(
            (const __attribute__((address_space(1))) void*)(Bg + 16 * 1024 + k0),
            (__attribute__((address_space(3))) void*)Bsd1, 16, 0, 0);
        __syncthreads();
        short8 af[4], bf[4];
#pragma unroll
        for (int i = 0; i < 4; ++i)
            af[i] = *(const short8*)&As[(wr + i * 16 + lm) * 32 + quad * 8];
#pragma unroll
        for (int j = 0; j < 4; ++j)
            bf[j] = *(const short8*)&Bs[(wc + j * 16 + lm) * 32 + quad * 8];
#pragma unroll
        for (int i = 0; i < 4; ++i)
#pragma unroll
            for (int j = 0; j < 4; ++j)
                acc[i][j] = __builtin_amdgcn_mfma_f32_16x16x32_bf16(af[i], bf[j], acc[i][j], 0, 0, 0);
    }
    const int sel = col0 >> 10;
    const float* bias = (sel == 0) ? bs0 : (sel == 1) ? bs1 : (sel == 2) ? bs2 : bs3;
    const int act = (actmask >> sel) & 1;
    if (VT && sel == vtsel) {
        // transposed write: VT[b][h][dh][t], t-consecutive regs -> ushort4 stores
        const int b = row0 >> 11;
#pragma unroll
        for (int j = 0; j < 4; ++j) {
            const int c2 = (col0 + wc + j * 16 + lm) & 1023;
            const int h  = c2 >> 6;
            const int dh = c2 & 63;
            const float bj = bias[c2];
            u16* vrow = VT + ((size_t)(b * NH + h) * 64 + dh) * (size_t)S_;
#pragma unroll
            for (int i = 0; i < 4; ++i) {
                const int tb = (row0 & 2047) + wr + i * 16 + quad * 4;
                ushort4 o;
                o.x = f2bf(acc[i][j][0] + bj);
                o.y = f2bf(acc[i][j][1] + bj);
                o.z = f2bf(acc[i][j][2] + bj);
                o.w = f2bf(acc[i][j][3] + bj);
                *(ushort4*)&vrow[tb] = o;
            }
        }
    } else {
#pragma unroll
        for (int j = 0; j < 4; ++j) {
            const int colg = col0 + wc + j * 16 + lm;
            const float bj = bias[colg & 1023];
#pragma unroll
            for (int i = 0; i < 4; ++i) {
#pragma unroll
                for (int r = 0; r < 4; ++r) {
                    const int rowg = row0 + wr + i * 16 + quad * 4 + r;
                    float v = acc[i][j][r] + bj;
                    if (act) v = silu_fast(v);
                    outb[(size_t)rowg * ldo + colg] = f2bf(v);
                }
            }
        }
    }
}

// ---------------- 128x64 MFMA GEMM (for N=1024: w0, w2) ----------------
__global__ __launch_bounds__(256) void gemm64(
    const u16* __restrict__ A, int lda, const u16* __restrict__ WT,
    const float* __restrict__ bias,
    const float* __restrict__ res,
    float* __restrict__ outf, int ldo)
{
    __shared__ u16 As[128 * 32];
    __shared__ u16 Bs[64 * 32];
    const int tid  = threadIdx.x;
    const int wave = tid >> 6;
    const int lane = tid & 63;
    const int lm   = lane & 15;
    const int quad = lane >> 4;
    const int row0 = blockIdx.y << 7;
    const int col0 = blockIdx.x << 6;
    const int wr = (wave >> 1) << 6;
    const int wc = (wave & 1) << 5;

    const int srA = wave * 32 + (lane >> 2);
    const int srB = wave * 16 + (lane >> 2);
    const int skp = (lane & 3) << 3;
    const u16* Ag = A  + (size_t)(row0 + srA) * lda + skp;
    const u16* Bg = WT + (size_t)(col0 + srB) * 1024 + skp;
    u16* Asd0 = &As[(wave * 32) * 32];
    u16* Asd1 = &As[(wave * 32 + 16) * 32];
    u16* Bsd  = &Bs[(wave * 16) * 32];

    f32x4 acc[4][2] = {};

    for (int k0 = 0; k0 < 1024; k0 += 32) {
        __syncthreads();
        __builtin_amdgcn_global_load_lds(
            (const __attribute__((address_space(1))) void*)(Ag + k0),
            (__attribute__((address_space(3))) void*)Asd0, 16, 0, 0);
        __builtin_amdgcn_global_load_lds(
            (const __attribute__((address_space(1))) void*)(Ag + (size_t)16 * lda + k0),
            (__attribute__((address_space(3))) void*)Asd1, 16, 0, 0);
        __builtin_amdgcn_global_load_lds(
            (const __attribute__((address_space(1))) void*)(Bg + k0),
            (__attribute__((address_space(3))) void*)Bsd, 16, 0, 0);
        __syncthreads();
        short8 af[4], bf[2];
#pragma unroll
        for (int i = 0; i < 4; ++i)
            af[i] = *(const short8*)&As[(wr + i * 16 + lm) * 32 + quad * 8];
#pragma unroll
        for (int j = 0; j < 2; ++j)
            bf[j] = *(const short8*)&Bs[(wc + j * 16 + lm) * 32 + quad * 8];
#pragma unroll
        for (int i = 0; i < 4; ++i)
#pragma unroll
            for (int j = 0; j < 2; ++j)
                acc[i][j] = __builtin_amdgcn_mfma_f32_16x16x32_bf16(af[i], bf[j], acc[i][j], 0, 0, 0);
    }
#pragma unroll
    for (int j = 0; j < 2; ++j) {
        const int colg = col0 + wc + j * 16 + lm;
        const float bj = bias[colg];
#pragma unroll
        for (int i = 0; i < 4; ++i) {
#pragma unroll
            for (int r = 0; r < 4; ++r) {
                const int rowg = row0 + wr + i * 16 + quad * 4 + r;
                const size_t idx = (size_t)rowg * ldo + colg;
                float v = acc[i][j][r] + bj;
                if (res) v += res[idx];
                outf[idx] = v;
            }
        }
    }
}

// ---------------- MFMA SiLU attention, barrier-free (direct-global K/V) ----------------
// K tile (8KB) + V tile (8KB) fit L1 for the 4-wave reuse; the 16 same-(b,h) blocks
// reuse from L2 (XCD-chunk swizzle pins them to one XCD: 1MB footprint << 4MB L2).
// Pl is wave-private (rows [sw, sw+32)), so the t-loop has NO __syncthreads at all.
__global__ __launch_bounds__(256) void attn_mfma(
    const u16* __restrict__ qkvu, const u16* __restrict__ VT,
    const float* __restrict__ pb, u16* __restrict__ out)
{
    __shared__ u16 Pl[128 * 72];
    __shared__ float pbl[S_];
    const int tid  = threadIdx.x;
    const int wave = tid >> 6;
    const int lane = tid & 63;
    const int lm   = lane & 15;
    const int quad = lane >> 4;
    // XCD-chunk swizzle: flat id 0..511 round-robins XCDs; give XCD c the contiguous
    // work chunk [64c, 64c+64) so each (b,h)'s 16 s0-blocks share one XCD's L2.
    const int flat = blockIdx.x + (blockIdx.y << 4) + (blockIdx.z << 8);
    const int work = ((flat & 7) << 6) + (flat >> 3);
    const int s0 = (work & 15) << 7;
    const int h  = (work >> 4) & 15;
    const int b  = work >> 8;
    const size_t base = (size_t)b * S_ * LQ + (size_t)h * DH;
    const u16* q  = qkvu + base;
    const u16* kg = qkvu + base + 1024;
    const u16* vt = VT + (size_t)(b * NH + h) * 64 * S_;
    const int sw = wave << 5;

    for (int i = tid; i < S_; i += 256) pbl[i] = pb[(size_t)i * NH + h];

    short8 qf[2][2];
#pragma unroll
    for (int ns = 0; ns < 2; ++ns)
#pragma unroll
        for (int kk = 0; kk < 2; ++kk)
            qf[ns][kk] = *(const short8*)&q[(size_t)(s0 + sw + ns * 16 + lm) * LQ + kk * 32 + quad * 8];

    // per-lane fragment base pointers: row=lm, col=quad*8 (16B contiguous slices)
    const u16* kgf = kg + (size_t)lm * LQ + quad * 8;
    const u16* vtf = vt + (size_t)lm * S_ + quad * 8;

    f32x4 accO[2][4] = {};
    __syncthreads();   // pbl ready; only barrier in the kernel

#pragma unroll 1
    for (int t0 = 0; t0 < S_; t0 += 64) {
        // V fragments issued first: consumed last (PV), latency hides under QK+silu
        short8 vf[4][2];
#pragma unroll
        for (int nj = 0; nj < 4; ++nj) {
            vf[nj][0] = *(const short8*)(vtf + (size_t)(nj * 16) * S_ + t0);
            vf[nj][1] = *(const short8*)(vtf + (size_t)(nj * 16) * S_ + t0 + 32);
        }
        short8 kf[4][2];
#pragma unroll
        for (int mt = 0; mt < 4; ++mt) {
            kf[mt][0] = *(const short8*)(kgf + (size_t)(t0 + mt * 16) * LQ);
            kf[mt][1] = *(const short8*)(kgf + (size_t)(t0 + mt * 16) * LQ + 32);
        }
        f32x4 st[4][2] = {};
#pragma unroll
        for (int mt = 0; mt < 4; ++mt)
#pragma unroll
            for (int ns = 0; ns < 2; ++ns)
#pragma unroll
                for (int kk = 0; kk < 2; ++kk)
                    st[mt][ns] = __builtin_amdgcn_mfma_f32_16x16x32_bf16(kf[mt][kk], qf[ns][kk], st[mt][ns], 0, 0, 0);
        // P = silu(0.125*S + pb): fast path — a = fma(st,.125,pb);
        // e = exp2(fma(st,-.125*log2e, pb*-log2e)); p = a*rcp(1+e)
#pragma unroll
        for (int mt = 0; mt < 4; ++mt) {
            const int tl = mt * 16 + quad * 4;
            float4 pbv = *(const float4*)&pbl[t0 + tl];
            const float pbr[4]  = {pbv.x, pbv.y, pbv.z, pbv.w};
            const float pbr2[4] = {pbv.x * -LOG2E, pbv.y * -LOG2E,
                                   pbv.z * -LOG2E, pbv.w * -LOG2E};
#pragma unroll
            for (int ns = 0; ns < 2; ++ns) {
                float p[4];
#pragma unroll
                for (int r = 0; r < 4; ++r) {
                    const float a = fmaf(st[mt][ns][r], 0.125f, pbr[r]);
                    const float e = __builtin_amdgcn_exp2f(
                        fmaf(st[mt][ns][r], -0.125f * LOG2E, pbr2[r]));
                    p[r] = a * __builtin_amdgcn_rcpf(1.0f + e);
                }
                uint2 pk;
                pk.x = pack2bf(p[0], p[1]);
                pk.y = pack2bf(p[2], p[3]);
                *(uint2*)&Pl[(sw + ns * 16 + lm) * 72 + tl] = pk;
            }
        }
        short8 pf[2][2];
#pragma unroll
        for (int mi = 0; mi < 2; ++mi)
#pragma unroll
            for (int kk = 0; kk < 2; ++kk)
                pf[mi][kk] = *(const short8*)&Pl[(sw + mi * 16 + lm) * 72 + kk * 32 + quad * 8];
#pragma unroll
        for (int mi = 0; mi < 2; ++mi)
#pragma unroll
            for (int nj = 0; nj < 4; ++nj)
#pragma unroll
                for (int kk = 0; kk < 2; ++kk)
                    accO[mi][nj] = __builtin_amdgcn_mfma_f32_16x16x32_bf16(pf[mi][kk], vf[nj][kk], accO[mi][nj], 0, 0, 0);
    }
#pragma unroll
    for (int mi = 0; mi < 2; ++mi)
#pragma unroll
        for (int nj = 0; nj < 4; ++nj)
#pragma unroll
            for (int r = 0; r < 4; ++r) {
                const int s = s0 + sw + mi * 16 + quad * 4 + r;
                out[base + (size_t)s * LQ + nj * 16 + lm] = f2bf(accO[mi][nj][r]);
            }
}

// ---------------- SwiGLU on QKVU: x1=cols[0,1024), x2=[1024,2048) -> [2048,3072) ----
__global__ __launch_bounds__(256) void swiglu_kernel(u16* __restrict__ qkvu)
{
    const size_t e = ((size_t)blockIdx.x * 256 + threadIdx.x) << 2;
    const size_t r = e >> 10;
    const int    c = (int)(e & 1023);
    ushort4 a = *(const ushort4*)&qkvu[r * LQ + c];
    ushort4 b = *(const ushort4*)&qkvu[r * LQ + 1024 + c];
    ushort4 o;
    o.x = f2bf(silu_fast(bf2f(a.x)) * bf2f(b.x));
    o.y = f2bf(silu_fast(bf2f(a.y)) * bf2f(b.y));
    o.z = f2bf(silu_fast(bf2f(a.z)) * bf2f(b.z));
    o.w = f2bf(silu_fast(bf2f(a.w)) * bf2f(b.w));
    *(ushort4*)&qkvu[r * LQ + 2048 + c] = o;
}

extern "C" void kernel_launch(void* const* d_in, const int* in_sizes, int n_in,
                              void* d_out, int out_size, void* d_ws, size_t ws_size,
                              hipStream_t stream)
{
    const float* x      = (const float*)d_in[0];
    const float* pb     = (const float*)d_in[2];
    const float* wq     = (const float*)d_in[3];
    const float* bq     = (const float*)d_in[4];
    const float* wk     = (const float*)d_in[5];
    const float* bk     = (const float*)d_in[6];
    const float* wv     = (const float*)d_in[7];
    const float* bv     = (const float*)d_in[8];
    const float* wu     = (const float*)d_in[9];
    const float* bu     = (const float*)d_in[10];
    const float* g_ams  = (const float*)d_in[11];
    const float* w0     = (const float*)d_in[12];
    const float* b0     = (const float*)d_in[13];
    const float* w1     = (const float*)d_in[14];
    const float* b1     = (const float*)d_in[15];
    const float* w2     = (const float*)d_in[16];
    const float* b2     = (const float*)d_in[17];
    const float* g_mffn = (const float*)d_in[18];
    float* OUT = (float*)d_out;
    u16*   VT  = (u16*)d_out;              // VT[b][h][64][2048] (8 MB) — dead after attn

    const size_t MI = 1024 * 1024;
    u16* WS   = (u16*)d_ws;                // 56 MB total
    u16* wT4  = WS;
    u16* w0T  = WS + 4 * MI;
    u16* w2T  = WS + 5 * MI;
    u16* w1T  = WS + 6 * MI;
    u16* A0   = WS + 8 * MI;
    u16* QKVU = WS + 12 * MI;

    dim3 blk(256);

    transpose_all_kernel<<<dim3(16, 16, 8), blk, 0, stream>>>(
        wq, wk, wv, wu, w0, w2, w1, wT4, w0T, w2T, w1T);

    rmsnorm_kernel<<<ROWS, blk, 0, stream>>>(x, nullptr, D, g_ams, nullptr, 0, A0, D);
    gemm128<<<dim3(32, 32), blk, 0, stream>>>(A0, wT4, bq, bk, bv, bu,
                                              QKVU, LQ, 0b1000, VT, 2);
    attn_mfma<<<dim3(S_ / 128, NH, B_), blk, 0, stream>>>(QKVU, VT, pb, QKVU);
    rmsnorm_kernel<<<ROWS, blk, 0, stream>>>(nullptr, QKVU, LQ, g_ams, QKVU + 3072, LQ, A0, D);
    gemm64<<<dim3(16, 32), blk, 0, stream>>>(A0, D, w0T, b0, x, OUT, D);
    rmsnorm_kernel<<<ROWS, blk, 0, stream>>>(OUT, nullptr, D, g_mffn, nullptr, 0, A0, D);
    gemm128<<<dim3(16, 32), blk, 0, stream>>>(A0, w1T, b1, b1 + 1024, b1, b1,
                                              QKVU, LQ, 0, nullptr, -1);
    swiglu_kernel<<<ROWS * D / 1024, blk, 0, stream>>>(QKVU);
    gemm64<<<dim3(16, 32), blk, 0, stream>>>(QKVU + 2048, LQ, w2T, b2, OUT, OUT, D);
    (void)ws_size; (void)in_sizes; (void)n_in; (void)out_size;
}

// Round 2
// 352.938 us; speedup vs baseline: 1.1129x; 1.1129x over previous
//
#include <hip/hip_runtime.h>
#include <stdint.h>
#include <math.h>

// FuXi block on MI355X, round 11: staged K/V restored + register P-transpose.
// r10 post-mortem: direct-global K/V fragments = 16-row strided gathers, latency-bound
// (VALU 38%, Mfma 10%, FETCH 12.8MB all-L2). Staging via global_load_lds was load-bearing.
// r9 vs r10 conflict counts identical (3145728) => ALL bank conflicts were the Pl
// round-trip; K/V swizzled staging is conflict-free.
// r11: (a) restore r9 staging; (b) replace Pl LDS transpose with ds_bpermute in-register
// quad-exchange (16 bperm + 8 cndmask/tile, no LDS, no conflicts); (c) 64-row q-blocks
// (grid 1024) + pb pre-transposed to global pbT[h][t] => LDS 32KB, 4 blocks/CU.

#define D    1024
#define NH   16
#define DH   64
#define B_   2
#define S_   2048
#define ROWS 4096
#define LQ   4096          // QKVU row stride
#define EPSR 1e-8f

typedef unsigned short u16;
typedef __attribute__((ext_vector_type(8))) short short8;
typedef __attribute__((ext_vector_type(4))) float f32x4;

__device__ __forceinline__ float bf2f(u16 u) {
    union { uint32_t i; float f; } c; c.i = ((uint32_t)u) << 16; return c.f;
}
__device__ __forceinline__ u16 f2bf(float f) {
    union { float f; uint32_t i; } c; c.f = f;
    uint32_t x = c.i;
    x += 0x7fffu + ((x >> 16) & 1u);
    return (u16)(x >> 16);
}
// pack two f32 -> (bf16(a) | bf16(b)<<16), round-half-up via +0x8000 then v_perm
__device__ __forceinline__ uint32_t pack2bf(float a, float b) {
    union { float f; uint32_t i; } ca, cb; ca.f = a; cb.f = b;
    return __builtin_amdgcn_perm(cb.i + 0x8000u, ca.i + 0x8000u, 0x07060302);
}
#define LOG2E 1.44269504f
// fast silu: one v_exp (=2^x) + one v_rcp, no IEEE divide
__device__ __forceinline__ float silu_fast(float v) {
    return v * __builtin_amdgcn_rcpf(1.0f + __builtin_amdgcn_exp2f(v * -LOG2E));
}

// ---------------- fused weight prep: 7 transposes in one dispatch ----------------
__global__ __launch_bounds__(256) void transpose_all_kernel(
    const float* __restrict__ wq, const float* __restrict__ wk,
    const float* __restrict__ wv, const float* __restrict__ wu,
    const float* __restrict__ w0, const float* __restrict__ w2,
    const float* __restrict__ w1,
    u16* __restrict__ wT4, u16* __restrict__ w0T,
    u16* __restrict__ w2T, u16* __restrict__ w1T)
{
    const unsigned MI = 1u << 20;
    const int z = blockIdx.z;
    const float* W; u16* WT; int N; int noff = 0;
    switch (z) {
        case 0: W = wq; WT = wT4;          N = 1024; break;
        case 1: W = wk; WT = wT4 + 1 * MI; N = 1024; break;
        case 2: W = wv; WT = wT4 + 2 * MI; N = 1024; break;
        case 3: W = wu; WT = wT4 + 3 * MI; N = 1024; break;
        case 4: W = w0; WT = w0T;          N = 1024; break;
        case 5: W = w2; WT = w2T;          N = 1024; break;
        case 6: W = w1; WT = w1T;          N = 2048; noff = 0;    break;
        default:W = w1; WT = w1T;          N = 2048; noff = 1024; break;
    }
    __shared__ float T[64][65];
    const int tid = threadIdx.x;
    const int n0 = (blockIdx.x << 6) + noff;
    const int k0 = blockIdx.y << 6;
    const int rr = tid >> 4;
    const int cc = (tid & 15) << 2;
#pragma unroll
    for (int l = 0; l < 4; ++l) {
        const int r = rr + (l << 4);
        float4 v = *(const float4*)&W[(size_t)(k0 + r) * N + n0 + cc];
        T[cc + 0][r] = v.x; T[cc + 1][r] = v.y;
        T[cc + 2][r] = v.z; T[cc + 3][r] = v.w;
    }
    __syncthreads();
    const int n  = tid >> 2;
    const int ks = (tid & 3) << 4;
#pragma unroll
    for (int m = 0; m < 4; ++m) {
        const int k = ks + (m << 2);
        float4 v = *(const float4*)&T[n][k];
        ushort4 o;
        o.x = f2bf(v.x); o.y = f2bf(v.y); o.z = f2bf(v.z); o.w = f2bf(v.w);
        *(ushort4*)&WT[(size_t)(n0 + n) * 1024 + k0 + k] = o;
    }
}

// ---------------- pb transpose: pbT[h][t] = pb[t][h] (L2-resident table) ----------
__global__ __launch_bounds__(256) void pbt_kernel(
    const float* __restrict__ pb, float* __restrict__ pbT)
{
    const int tid = threadIdx.x;
    const int r = (blockIdx.x << 7) + (tid >> 1);   // 0..2047
    const int c0 = (tid & 1) << 3;                  // 0 or 8
    float4 v0 = *(const float4*)&pb[(size_t)r * NH + c0];
    float4 v1 = *(const float4*)&pb[(size_t)r * NH + c0 + 4];
    pbT[(size_t)(c0 + 0) * S_ + r] = v0.x;
    pbT[(size_t)(c0 + 1) * S_ + r] = v0.y;
    pbT[(size_t)(c0 + 2) * S_ + r] = v0.z;
    pbT[(size_t)(c0 + 3) * S_ + r] = v0.w;
    pbT[(size_t)(c0 + 4) * S_ + r] = v1.x;
    pbT[(size_t)(c0 + 5) * S_ + r] = v1.y;
    pbT[(size_t)(c0 + 6) * S_ + r] = v1.z;
    pbT[(size_t)(c0 + 7) * S_ + r] = v1.w;
}

// ---------------- RMSNorm ----------------
__global__ __launch_bounds__(256) void rmsnorm_kernel(
    const float* __restrict__ inf, const u16* __restrict__ inb, int ldi,
    const float* __restrict__ g,
    const u16* __restrict__ mul, int ldm,
    u16* __restrict__ out, int ldo)
{
    const int row = blockIdx.x;
    const int tid = threadIdx.x;
    const int c = tid << 2;
    float x0, x1, x2, x3;
    if (inb) {
        ushort4 xi = *(const ushort4*)&inb[(size_t)row * ldi + c];
        x0 = bf2f(xi.x); x1 = bf2f(xi.y); x2 = bf2f(xi.z); x3 = bf2f(xi.w);
    } else {
        float4 xi = *(const float4*)&inf[(size_t)row * ldi + c];
        x0 = xi.x; x1 = xi.y; x2 = xi.z; x3 = xi.w;
    }
    float ss = x0*x0 + x1*x1 + x2*x2 + x3*x3;
#pragma unroll
    for (int off = 32; off > 0; off >>= 1) ss += __shfl_down(ss, off, 64);
    __shared__ float red[4];
    if ((tid & 63) == 0) red[tid >> 6] = ss;
    __syncthreads();
    float r = rsqrtf((red[0] + red[1] + red[2] + red[3]) * (1.0f / D) + EPSR);
    float4 gv = *(const float4*)&g[c];
    float v0 = x0 * r * gv.x, v1 = x1 * r * gv.y, v2 = x2 * r * gv.z, v3 = x3 * r * gv.w;
    if (mul) {
        ushort4 mi = *(const ushort4*)&mul[(size_t)row * ldm + c];
        v0 *= bf2f(mi.x); v1 *= bf2f(mi.y); v2 *= bf2f(mi.z); v3 *= bf2f(mi.w);
    }
    ushort4 o;
    o.x = f2bf(v0); o.y = f2bf(v1); o.z = f2bf(v2); o.w = f2bf(v3);
    *(ushort4*)&out[(size_t)row * ldo + c] = o;
}

// ---------------- 128x128 MFMA GEMM (m97 motif), bf16 out ----------------
__global__ __launch_bounds__(256) void gemm128(
    const u16* __restrict__ A, const u16* __restrict__ WT,
    const float* __restrict__ bs0, const float* __restrict__ bs1,
    const float* __restrict__ bs2, const float* __restrict__ bs3,
    u16* __restrict__ outb, int ldo, int actmask,
    u16* __restrict__ VT, int vtsel)
{
    __shared__ u16 As[128 * 32];
    __shared__ u16 Bs[128 * 32];
    const int tid  = threadIdx.x;
    const int wave = tid >> 6;
    const int lane = tid & 63;
    const int lm   = lane & 15;
    const int quad = lane >> 4;
    const int row0 = blockIdx.y << 7;
    const int col0 = blockIdx.x << 7;
    const int wr = (wave >> 1) << 6;
    const int wc = (wave & 1) << 6;

    const int srow = wave * 32 + (lane >> 2);
    const int skp  = (lane & 3) << 3;
    const u16* Ag = A  + (size_t)(row0 + srow) * 1024 + skp;
    const u16* Bg = WT + (size_t)(col0 + srow) * 1024 + skp;
    u16* Asd0 = &As[(wave * 32) * 32];
    u16* Asd1 = &As[(wave * 32 + 16) * 32];
    u16* Bsd0 = &Bs[(wave * 32) * 32];
    u16* Bsd1 = &Bs[(wave * 32 + 16) * 32];

    f32x4 acc[4][4] = {};

    for (int k0 = 0; k0 < 1024; k0 += 32) {
        __syncthreads();
        __builtin_amdgcn_global_load_lds(
            (const __attribute__((address_space(1))) void*)(Ag + k0),
            (__attribute__((address_space(3))) void*)Asd0, 16, 0, 0);
        __builtin_amdgcn_global_load_lds(
            (const __attribute__((address_space(1))) void*)(Ag + 16 * 1024 + k0),
            (__attribute__((address_space(3))) void*)Asd1, 16, 0, 0);
        __builtin_amdgcn_global_load_lds(
            (const __attribute__((address_space(1))) void*)(Bg + k0),
            (__attribute__((address_space(3))) void*)Bsd0, 16, 0, 0);
        __builtin_amdgcn_global_load_lds(
            (const __attribute__((address_space(1))) void*)(Bg + 16 * 1024 + k0),
            (__attribute__((address_space(3))) void*)Bsd1, 16, 0, 0);
        __syncthreads();
        short8 af[4], bf[4];
#pragma unroll
        for (int i = 0; i < 4; ++i)
            af[i] = *(const short8*)&As[(wr + i * 16 + lm) * 32 + quad * 8];
#pragma unroll
        for (int j = 0; j < 4; ++j)
            bf[j] = *(const short8*)&Bs[(wc + j * 16 + lm) * 32 + quad * 8];
#pragma unroll
        for (int i = 0; i < 4; ++i)
#pragma unroll
            for (int j = 0; j < 4; ++j)
                acc[i][j] = __builtin_amdgcn_mfma_f32_16x16x32_bf16(af[i], bf[j], acc[i][j], 0, 0, 0);
    }
    const int sel = col0 >> 10;
    const float* bias = (sel == 0) ? bs0 : (sel == 1) ? bs1 : (sel == 2) ? bs2 : bs3;
    const int act = (actmask >> sel) & 1;
    if (VT && sel == vtsel) {
        // transposed write: VT[b][h][dh][t], t-consecutive regs -> ushort4 stores
        const int b = row0 >> 11;
#pragma unroll
        for (int j = 0; j < 4; ++j) {
            const int c2 = (col0 + wc + j * 16 + lm) & 1023;
            const int h  = c2 >> 6;
            const int dh = c2 & 63;
            const float bj = bias[c2];
            u16* vrow = VT + ((size_t)(b * NH + h) * 64 + dh) * (size_t)S_;
#pragma unroll
            for (int i = 0; i < 4; ++i) {
                const int tb = (row0 & 2047) + wr + i * 16 + quad * 4;
                ushort4 o;
                o.x = f2bf(acc[i][j][0] + bj);
                o.y = f2bf(acc[i][j][1] + bj);
                o.z = f2bf(acc[i][j][2] + bj);
                o.w = f2bf(acc[i][j][3] + bj);
                *(ushort4*)&vrow[tb] = o;
            }
        }
    } else {
#pragma unroll
        for (int j = 0; j < 4; ++j) {
            const int colg = col0 + wc + j * 16 + lm;
            const float bj = bias[colg & 1023];
#pragma unroll
            for (int i = 0; i < 4; ++i) {
#pragma unroll
                for (int r = 0; r < 4; ++r) {
                    const int rowg = row0 + wr + i * 16 + quad * 4 + r;
                    float v = acc[i][j][r] + bj;
                    if (act) v = silu_fast(v);
                    outb[(size_t)rowg * ldo + colg] = f2bf(v);
                }
            }
        }
    }
}

// ---------------- 128x64 MFMA GEMM (for N=1024: w0, w2) ----------------
__global__ __launch_bounds__(256) void gemm64(
    const u16* __restrict__ A, int lda, const u16* __restrict__ WT,
    const float* __restrict__ bias,
    const float* __restrict__ res,
    float* __restrict__ outf, int ldo)
{
    __shared__ u16 As[128 * 32];
    __shared__ u16 Bs[64 * 32];
    const int tid  = threadIdx.x;
    const int wave = tid >> 6;
    const int lane = tid & 63;
    const int lm   = lane & 15;
    const int quad = lane >> 4;
    const int row0 = blockIdx.y << 7;
    const int col0 = blockIdx.x << 6;
    const int wr = (wave >> 1) << 6;
    const int wc = (wave & 1) << 5;

    const int srA = wave * 32 + (lane >> 2);
    const int srB = wave * 16 + (lane >> 2);
    const int skp = (lane & 3) << 3;
    const u16* Ag = A  + (size_t)(row0 + srA) * lda + skp;
    const u16* Bg = WT + (size_t)(col0 + srB) * 1024 + skp;
    u16* Asd0 = &As[(wave * 32) * 32];
    u16* Asd1 = &As[(wave * 32 + 16) * 32];
    u16* Bsd  = &Bs[(wave * 16) * 32];

    f32x4 acc[4][2] = {};

    for (int k0 = 0; k0 < 1024; k0 += 32) {
        __syncthreads();
        __builtin_amdgcn_global_load_lds(
            (const __attribute__((address_space(1))) void*)(Ag + k0),
            (__attribute__((address_space(3))) void*)Asd0, 16, 0, 0);
        __builtin_amdgcn_global_load_lds(
            (const __attribute__((address_space(1))) void*)(Ag + (size_t)16 * lda + k0),
            (__attribute__((address_space(3))) void*)Asd1, 16, 0, 0);
        __builtin_amdgcn_global_load_lds(
            (const __attribute__((address_space(1))) void*)(Bg + k0),
            (__attribute__((address_space(3))) void*)Bsd, 16, 0, 0);
        __syncthreads();
        short8 af[4], bf[2];
#pragma unroll
        for (int i = 0; i < 4; ++i)
            af[i] = *(const short8*)&As[(wr + i * 16 + lm) * 32 + quad * 8];
#pragma unroll
        for (int j = 0; j < 2; ++j)
            bf[j] = *(const short8*)&Bs[(wc + j * 16 + lm) * 32 + quad * 8];
#pragma unroll
        for (int i = 0; i < 4; ++i)
#pragma unroll
            for (int j = 0; j < 2; ++j)
                acc[i][j] = __builtin_amdgcn_mfma_f32_16x16x32_bf16(af[i], bf[j], acc[i][j], 0, 0, 0);
    }
#pragma unroll
    for (int j = 0; j < 2; ++j) {
        const int colg = col0 + wc + j * 16 + lm;
        const float bj = bias[colg];
#pragma unroll
        for (int i = 0; i < 4; ++i) {
#pragma unroll
            for (int r = 0; r < 4; ++r) {
                const int rowg = row0 + wr + i * 16 + quad * 4 + r;
                const size_t idx = (size_t)rowg * ldo + colg;
                float v = acc[i][j][r] + bj;
                if (res) v += res[idx];
                outf[idx] = v;
            }
        }
    }
}

// ---------------- MFMA SiLU attention: staged K/V + register P-transpose ----------
// 64 q-rows/block (16/wave), grid 1024, LDS 32KB -> 4 blocks/CU (16 waves).
// P transpose (C-layout -> A-fragment) done with ds_bpermute across quads at fixed lm:
//   target (quad,w) word <- stp[2kk+(quad>>1)][w&1] from lane lm+16*(2*(quad&1)+(w>>1)).
__global__ __launch_bounds__(256, 4) void attn_mfma(
    const u16* __restrict__ qkvu, const u16* __restrict__ VT,
    const float* __restrict__ pbT, u16* __restrict__ out)
{
    __shared__ u16 Ks[2][64 * 64];
    __shared__ u16 Vs[2][64 * 64];
    const int tid  = threadIdx.x;
    const int wave = tid >> 6;
    const int lane = tid & 63;
    const int lm   = lane & 15;
    const int quad = lane >> 4;
    // XCD-chunk swizzle (1024 % 8 == 0 -> bijective): each XCD gets 128 consecutive
    // work ids = 4 (b,h) groups x 32 q-blocks; K+V footprint 2MB/XCD << 4MB L2.
    const int flat = blockIdx.x + (blockIdx.y << 5) + (blockIdx.z << 9);
    const int work = ((flat & 7) << 7) + (flat >> 3);
    const int s0 = (work & 31) << 6;
    const int h  = (work >> 5) & 15;
    const int b  = work >> 9;
    const size_t base = (size_t)b * S_ * LQ + (size_t)h * DH;
    const u16* q  = qkvu + base;
    const u16* kg = qkvu + base + 1024;
    const u16* vt = VT + (size_t)(b * NH + h) * 64 * S_;
    const float* pbh = pbT + (size_t)h * S_;

    short8 qf[2];
#pragma unroll
    for (int kk = 0; kk < 2; ++kk)
        qf[kk] = *(const short8*)&q[(size_t)(s0 + wave * 16 + lm) * LQ + kk * 32 + quad * 8];

    const int lr  = lane >> 3;
    const int gch = (lane & 7) ^ lr;
    const u16* kg0 = kg + (size_t)(16 * wave + lr) * LQ + gch * 8;
    const u16* vg0 = vt + (size_t)(16 * wave + lr) * S_ + gch * 8;
    const int cof0 = ((0 * 4 + quad) ^ (lm & 7)) * 8;
    const int cof1 = ((1 * 4 + quad) ^ (lm & 7)) * 8;
    const int a0   = (lm + ((quad & 1) << 5)) << 2;  // bpermute byte addr, quad_src lo
    const bool hi  = quad >= 2;

#define GLDS(gp, lp) __builtin_amdgcn_global_load_lds( \
        (const __attribute__((address_space(1))) void*)(gp), \
        (__attribute__((address_space(3))) void*)(lp), 16, 0, 0)

    GLDS(kg0,                     &Ks[0][(16 * wave) * 64]);
    GLDS(kg0 + (size_t)8 * LQ,    &Ks[0][(16 * wave + 8) * 64]);
    GLDS(vg0,                     &Vs[0][(16 * wave) * 64]);
    GLDS(vg0 + (size_t)8 * S_,    &Vs[0][(16 * wave + 8) * 64]);

    f32x4 accO[4] = {};
    __syncthreads();

    for (int t0 = 0; t0 < S_; t0 += 64) {
        const int ib = (t0 >> 6) & 1;
        const int nb = ib ^ 1;
        // pb slice for this tile (L1/L2-hit broadcast); consumed after QK MFMA
        float4 pbv[4];
#pragma unroll
        for (int mt = 0; mt < 4; ++mt)
            pbv[mt] = *(const float4*)&pbh[t0 + mt * 16 + quad * 4];
        if (t0 + 64 < S_) {
            const size_t tn = (size_t)(t0 + 64);
            GLDS(kg0 + tn * LQ,             &Ks[nb][(16 * wave) * 64]);
            GLDS(kg0 + (tn + 8) * LQ,       &Ks[nb][(16 * wave + 8) * 64]);
            GLDS(vg0 + tn,                  &Vs[nb][(16 * wave) * 64]);
            GLDS(vg0 + tn + (size_t)8 * S_, &Vs[nb][(16 * wave + 8) * 64]);
        }
        short8 kf[4][2];
#pragma unroll
        for (int mt = 0; mt < 4; ++mt) {
            kf[mt][0] = *(const short8*)&Ks[ib][(mt * 16 + lm) * 64 + cof0];
            kf[mt][1] = *(const short8*)&Ks[ib][(mt * 16 + lm) * 64 + cof1];
        }
        f32x4 st[4] = {};
#pragma unroll
        for (int mt = 0; mt < 4; ++mt)
#pragma unroll
            for (int kk = 0; kk < 2; ++kk)
                st[mt] = __builtin_amdgcn_mfma_f32_16x16x32_bf16(kf[mt][kk], qf[kk], st[mt], 0, 0, 0);
        // P = silu(0.125*S + pb), packed to bf16 pairs in registers
        int stp[4][2];
#pragma unroll
        for (int mt = 0; mt < 4; ++mt) {
            const float pbr[4] = {pbv[mt].x, pbv[mt].y, pbv[mt].z, pbv[mt].w};
            float p[4];
#pragma unroll
            for (int r = 0; r < 4; ++r) {
                const float a = fmaf(st[mt][r], 0.125f, pbr[r]);
                const float e = __builtin_amdgcn_exp2f(a * -LOG2E);
                p[r] = a * __builtin_amdgcn_rcpf(1.0f + e);
            }
            stp[mt][0] = (int)pack2bf(p[0], p[1]);
            stp[mt][1] = (int)pack2bf(p[2], p[3]);
        }
        // register transpose: C-layout (q=lm, t=quad*4+r per mt) -> A-fragment
        // (q=lm, t=kk*32+quad*8+j). Pure quad-permute at fixed lm.
        short8 pf[2];
#pragma unroll
        for (int kk = 0; kk < 2; ++kk) {
            const int e0 = stp[2 * kk][0],     e1 = stp[2 * kk][1];
            const int o0 = stp[2 * kk + 1][0], o1 = stp[2 * kk + 1][1];
            const int w0a = __builtin_amdgcn_ds_bpermute(a0,      e0);
            const int w0b = __builtin_amdgcn_ds_bpermute(a0,      o0);
            const int w1a = __builtin_amdgcn_ds_bpermute(a0,      e1);
            const int w1b = __builtin_amdgcn_ds_bpermute(a0,      o1);
            const int w2a = __builtin_amdgcn_ds_bpermute(a0 + 64, e0);
            const int w2b = __builtin_amdgcn_ds_bpermute(a0 + 64, o0);
            const int w3a = __builtin_amdgcn_ds_bpermute(a0 + 64, e1);
            const int w3b = __builtin_amdgcn_ds_bpermute(a0 + 64, o1);
            int4 pw;
            pw.x = hi ? w0b : w0a;
            pw.y = hi ? w1b : w1a;
            pw.z = hi ? w2b : w2a;
            pw.w = hi ? w3b : w3a;
            pf[kk] = *(const short8*)&pw;
        }
        short8 vf[4][2];
#pragma unroll
        for (int nj = 0; nj < 4; ++nj) {
            vf[nj][0] = *(const short8*)&Vs[ib][(nj * 16 + lm) * 64 + cof0];
            vf[nj][1] = *(const short8*)&Vs[ib][(nj * 16 + lm) * 64 + cof1];
        }
#pragma unroll
        for (int nj = 0; nj < 4; ++nj)
#pragma unroll
            for (int kk = 0; kk < 2; ++kk)
                accO[nj] = __builtin_amdgcn_mfma_f32_16x16x32_bf16(pf[kk], vf[nj][kk], accO[nj], 0, 0, 0);
        __syncthreads();
    }
#undef GLDS
    const int srow = s0 + wave * 16 + quad * 4;
#pragma unroll
    for (int nj = 0; nj < 4; ++nj)
#pragma unroll
        for (int r = 0; r < 4; ++r)
            out[base + (size_t)(srow + r) * LQ + nj * 16 + lm] = f2bf(accO[nj][r]);
}

// ---------------- SwiGLU on QKVU: x1=cols[0,1024), x2=[1024,2048) -> [2048,3072) ----
__global__ __launch_bounds__(256) void swiglu_kernel(u16* __restrict__ qkvu)
{
    const size_t e = ((size_t)blockIdx.x * 256 + threadIdx.x) << 2;
    const size_t r = e >> 10;
    const int    c = (int)(e & 1023);
    ushort4 a = *(const ushort4*)&qkvu[r * LQ + c];
    ushort4 b = *(const ushort4*)&qkvu[r * LQ + 1024 + c];
    ushort4 o;
    o.x = f2bf(silu_fast(bf2f(a.x)) * bf2f(b.x));
    o.y = f2bf(silu_fast(bf2f(a.y)) * bf2f(b.y));
    o.z = f2bf(silu_fast(bf2f(a.z)) * bf2f(b.z));
    o.w = f2bf(silu_fast(bf2f(a.w)) * bf2f(b.w));
    *(ushort4*)&qkvu[r * LQ + 2048 + c] = o;
}

extern "C" void kernel_launch(void* const* d_in, const int* in_sizes, int n_in,
                              void* d_out, int out_size, void* d_ws, size_t ws_size,
                              hipStream_t stream)
{
    const float* x      = (const float*)d_in[0];
    const float* pb     = (const float*)d_in[2];
    const float* wq     = (const float*)d_in[3];
    const float* bq     = (const float*)d_in[4];
    const float* wk     = (const float*)d_in[5];
    const float* bk     = (const float*)d_in[6];
    const float* wv     = (const float*)d_in[7];
    const float* bv     = (const float*)d_in[8];
    const float* wu     = (const float*)d_in[9];
    const float* bu     = (const float*)d_in[10];
    const float* g_ams  = (const float*)d_in[11];
    const float* w0     = (const float*)d_in[12];
    const float* b0     = (const float*)d_in[13];
    const float* w1     = (const float*)d_in[14];
    const float* b1     = (const float*)d_in[15];
    const float* w2     = (const float*)d_in[16];
    const float* b2     = (const float*)d_in[17];
    const float* g_mffn = (const float*)d_in[18];
    float* OUT = (float*)d_out;
    u16*   VT  = (u16*)d_out;              // VT[b][h][64][2048] (8 MB) — dead after attn
    float* pbT = (float*)((u16*)d_out + 4 * (1u << 20));  // 128KB at +8MB — dead after attn

    const size_t MI = 1024 * 1024;
    u16* WS   = (u16*)d_ws;                // 56 MB total
    u16* wT4  = WS;
    u16* w0T  = WS + 4 * MI;
    u16* w2T  = WS + 5 * MI;
    u16* w1T  = WS + 6 * MI;
    u16* A0   = WS + 8 * MI;
    u16* QKVU = WS + 12 * MI;

    dim3 blk(256);

    transpose_all_kernel<<<dim3(16, 16, 8), blk, 0, stream>>>(
        wq, wk, wv, wu, w0, w2, w1, wT4, w0T, w2T, w1T);
    pbt_kernel<<<16, blk, 0, stream>>>(pb, pbT);

    rmsnorm_kernel<<<ROWS, blk, 0, stream>>>(x, nullptr, D, g_ams, nullptr, 0, A0, D);
    gemm128<<<dim3(32, 32), blk, 0, stream>>>(A0, wT4, bq, bk, bv, bu,
                                              QKVU, LQ, 0b1000, VT, 2);
    attn_mfma<<<dim3(32, 16, 2), blk, 0, stream>>>(QKVU, VT, pbT, QKVU);
    rmsnorm_kernel<<<ROWS, blk, 0, stream>>>(nullptr, QKVU, LQ, g_ams, QKVU + 3072, LQ, A0, D);
    gemm64<<<dim3(16, 32), blk, 0, stream>>>(A0, D, w0T, b0, x, OUT, D);
    rmsnorm_kernel<<<ROWS, blk, 0, stream>>>(OUT, nullptr, D, g_mffn, nullptr, 0, A0, D);
    gemm128<<<dim3(16, 32), blk, 0, stream>>>(A0, w1T, b1, b1 + 1024, b1, b1,
                                              QKVU, LQ, 0, nullptr, -1);
    swiglu_kernel<<<ROWS * D / 1024, blk, 0, stream>>>(QKVU);
    gemm64<<<dim3(16, 32), blk, 0, stream>>>(QKVU + 2048, LQ, w2T, b2, OUT, OUT, D);
    (void)ws_size; (void)in_sizes; (void)n_in; (void)out_size;
}

// Round 4
// 343.847 us; speedup vs baseline: 1.1423x; 1.0264x over previous
//
#include <hip/hip_runtime.h>
#include <stdint.h>
#include <math.h>

// FuXi block on MI355X, round 13: r12 with the permlane32_swap operand order FIXED.
// r12 post-mortem: v_permlane32_swap_b32 VDST, VSRC swaps VDST.hi32 <-> VSRC.lo32.
// Required pairing is swap(VDST=pk[4m], VSRC=pk[4m+2]) so pk[4m] ends up as A-word0
// (low lane keeps t{16m,+1}; hi lane receives t{16m+8,9}) and pk[4m+2] as A-word2.
// r12 had the operands reversed -> P scrambled across t -> absmax 1.8. Single fix.
// Everything else identical to r12 (32x32 swapped-QK, in-register silu, 40KB LDS,
// 4 blocks/CU, grid 512, XCD chunk swizzle).

#define D    1024
#define NH   16
#define DH   64
#define B_   2
#define S_   2048
#define ROWS 4096
#define LQ   4096          // QKVU row stride
#define EPSR 1e-8f

typedef unsigned short u16;
typedef __attribute__((ext_vector_type(8))) short short8;
typedef __attribute__((ext_vector_type(4))) float f32x4;
typedef __attribute__((ext_vector_type(16))) float f32x16;
typedef __attribute__((ext_vector_type(4))) int int4v;

__device__ __forceinline__ float bf2f(u16 u) {
    union { uint32_t i; float f; } c; c.i = ((uint32_t)u) << 16; return c.f;
}
__device__ __forceinline__ u16 f2bf(float f) {
    union { float f; uint32_t i; } c; c.f = f;
    uint32_t x = c.i;
    x += 0x7fffu + ((x >> 16) & 1u);
    return (u16)(x >> 16);
}
#define LOG2E 1.44269504f
// fast silu: one v_exp (=2^x) + one v_rcp, no IEEE divide
__device__ __forceinline__ float silu_fast(float v) {
    return v * __builtin_amdgcn_rcpf(1.0f + __builtin_amdgcn_exp2f(v * -LOG2E));
}

// ---------------- fused weight prep: 7 transposes in one dispatch ----------------
__global__ __launch_bounds__(256) void transpose_all_kernel(
    const float* __restrict__ wq, const float* __restrict__ wk,
    const float* __restrict__ wv, const float* __restrict__ wu,
    const float* __restrict__ w0, const float* __restrict__ w2,
    const float* __restrict__ w1,
    u16* __restrict__ wT4, u16* __restrict__ w0T,
    u16* __restrict__ w2T, u16* __restrict__ w1T)
{
    const unsigned MI = 1u << 20;
    const int z = blockIdx.z;
    const float* W; u16* WT; int N; int noff = 0;
    switch (z) {
        case 0: W = wq; WT = wT4;          N = 1024; break;
        case 1: W = wk; WT = wT4 + 1 * MI; N = 1024; break;
        case 2: W = wv; WT = wT4 + 2 * MI; N = 1024; break;
        case 3: W = wu; WT = wT4 + 3 * MI; N = 1024; break;
        case 4: W = w0; WT = w0T;          N = 1024; break;
        case 5: W = w2; WT = w2T;          N = 1024; break;
        case 6: W = w1; WT = w1T;          N = 2048; noff = 0;    break;
        default:W = w1; WT = w1T;          N = 2048; noff = 1024; break;
    }
    __shared__ float T[64][65];
    const int tid = threadIdx.x;
    const int n0 = (blockIdx.x << 6) + noff;
    const int k0 = blockIdx.y << 6;
    const int rr = tid >> 4;
    const int cc = (tid & 15) << 2;
#pragma unroll
    for (int l = 0; l < 4; ++l) {
        const int r = rr + (l << 4);
        float4 v = *(const float4*)&W[(size_t)(k0 + r) * N + n0 + cc];
        T[cc + 0][r] = v.x; T[cc + 1][r] = v.y;
        T[cc + 2][r] = v.z; T[cc + 3][r] = v.w;
    }
    __syncthreads();
    const int n  = tid >> 2;
    const int ks = (tid & 3) << 4;
#pragma unroll
    for (int m = 0; m < 4; ++m) {
        const int k = ks + (m << 2);
        float4 v = *(const float4*)&T[n][k];
        ushort4 o;
        o.x = f2bf(v.x); o.y = f2bf(v.y); o.z = f2bf(v.z); o.w = f2bf(v.w);
        *(ushort4*)&WT[(size_t)(n0 + n) * 1024 + k0 + k] = o;
    }
}

// ---------------- pb transpose: pbT[h][t] = pb[t][h] (L2-resident table) ----------
__global__ __launch_bounds__(256) void pbt_kernel(
    const float* __restrict__ pb, float* __restrict__ pbT)
{
    const int tid = threadIdx.x;
    const int r = (blockIdx.x << 7) + (tid >> 1);   // 0..2047
    const int c0 = (tid & 1) << 3;                  // 0 or 8
    float4 v0 = *(const float4*)&pb[(size_t)r * NH + c0];
    float4 v1 = *(const float4*)&pb[(size_t)r * NH + c0 + 4];
    pbT[(size_t)(c0 + 0) * S_ + r] = v0.x;
    pbT[(size_t)(c0 + 1) * S_ + r] = v0.y;
    pbT[(size_t)(c0 + 2) * S_ + r] = v0.z;
    pbT[(size_t)(c0 + 3) * S_ + r] = v0.w;
    pbT[(size_t)(c0 + 4) * S_ + r] = v1.x;
    pbT[(size_t)(c0 + 5) * S_ + r] = v1.y;
    pbT[(size_t)(c0 + 6) * S_ + r] = v1.z;
    pbT[(size_t)(c0 + 7) * S_ + r] = v1.w;
}

// ---------------- RMSNorm ----------------
__global__ __launch_bounds__(256) void rmsnorm_kernel(
    const float* __restrict__ inf, const u16* __restrict__ inb, int ldi,
    const float* __restrict__ g,
    const u16* __restrict__ mul, int ldm,
    u16* __restrict__ out, int ldo)
{
    const int row = blockIdx.x;
    const int tid = threadIdx.x;
    const int c = tid << 2;
    float x0, x1, x2, x3;
    if (inb) {
        ushort4 xi = *(const ushort4*)&inb[(size_t)row * ldi + c];
        x0 = bf2f(xi.x); x1 = bf2f(xi.y); x2 = bf2f(xi.z); x3 = bf2f(xi.w);
    } else {
        float4 xi = *(const float4*)&inf[(size_t)row * ldi + c];
        x0 = xi.x; x1 = xi.y; x2 = xi.z; x3 = xi.w;
    }
    float ss = x0*x0 + x1*x1 + x2*x2 + x3*x3;
#pragma unroll
    for (int off = 32; off > 0; off >>= 1) ss += __shfl_down(ss, off, 64);
    __shared__ float red[4];
    if ((tid & 63) == 0) red[tid >> 6] = ss;
    __syncthreads();
    float r = rsqrtf((red[0] + red[1] + red[2] + red[3]) * (1.0f / D) + EPSR);
    float4 gv = *(const float4*)&g[c];
    float v0 = x0 * r * gv.x, v1 = x1 * r * gv.y, v2 = x2 * r * gv.z, v3 = x3 * r * gv.w;
    if (mul) {
        ushort4 mi = *(const ushort4*)&mul[(size_t)row * ldm + c];
        v0 *= bf2f(mi.x); v1 *= bf2f(mi.y); v2 *= bf2f(mi.z); v3 *= bf2f(mi.w);
    }
    ushort4 o;
    o.x = f2bf(v0); o.y = f2bf(v1); o.z = f2bf(v2); o.w = f2bf(v3);
    *(ushort4*)&out[(size_t)row * ldo + c] = o;
}

// ---------------- 128x128 MFMA GEMM (m97 motif), bf16 out ----------------
__global__ __launch_bounds__(256) void gemm128(
    const u16* __restrict__ A, const u16* __restrict__ WT,
    const float* __restrict__ bs0, const float* __restrict__ bs1,
    const float* __restrict__ bs2, const float* __restrict__ bs3,
    u16* __restrict__ outb, int ldo, int actmask,
    u16* __restrict__ VT, int vtsel)
{
    __shared__ u16 As[128 * 32];
    __shared__ u16 Bs[128 * 32];
    const int tid  = threadIdx.x;
    const int wave = tid >> 6;
    const int lane = tid & 63;
    const int lm   = lane & 15;
    const int quad = lane >> 4;
    const int row0 = blockIdx.y << 7;
    const int col0 = blockIdx.x << 7;
    const int wr = (wave >> 1) << 6;
    const int wc = (wave & 1) << 6;

    const int srow = wave * 32 + (lane >> 2);
    const int skp  = (lane & 3) << 3;
    const u16* Ag = A  + (size_t)(row0 + srow) * 1024 + skp;
    const u16* Bg = WT + (size_t)(col0 + srow) * 1024 + skp;
    u16* Asd0 = &As[(wave * 32) * 32];
    u16* Asd1 = &As[(wave * 32 + 16) * 32];
    u16* Bsd0 = &Bs[(wave * 32) * 32];
    u16* Bsd1 = &Bs[(wave * 32 + 16) * 32];

    f32x4 acc[4][4] = {};

    for (int k0 = 0; k0 < 1024; k0 += 32) {
        __syncthreads();
        __builtin_amdgcn_global_load_lds(
            (const __attribute__((address_space(1))) void*)(Ag + k0),
            (__attribute__((address_space(3))) void*)Asd0, 16, 0, 0);
        __builtin_amdgcn_global_load_lds(
            (const __attribute__((address_space(1))) void*)(Ag + 16 * 1024 + k0),
            (__attribute__((address_space(3))) void*)Asd1, 16, 0, 0);
        __builtin_amdgcn_global_load_lds(
            (const __attribute__((address_space(1))) void*)(Bg + k0),
            (__attribute__((address_space(3))) void*)Bsd0, 16, 0, 0);
        __builtin_amdgcn_global_load_lds(
            (const __attribute__((address_space(1))) void*)(Bg + 16 * 1024 + k0),
            (__attribute__((address_space(3))) void*)Bsd1, 16, 0, 0);
        __syncthreads();
        short8 af[4], bf[4];
#pragma unroll
        for (int i = 0; i < 4; ++i)
            af[i] = *(const short8*)&As[(wr + i * 16 + lm) * 32 + quad * 8];
#pragma unroll
        for (int j = 0; j < 4; ++j)
            bf[j] = *(const short8*)&Bs[(wc + j * 16 + lm) * 32 + quad * 8];
#pragma unroll
        for (int i = 0; i < 4; ++i)
#pragma unroll
            for (int j = 0; j < 4; ++j)
                acc[i][j] = __builtin_amdgcn_mfma_f32_16x16x32_bf16(af[i], bf[j], acc[i][j], 0, 0, 0);
    }
    const int sel = col0 >> 10;
    const float* bias = (sel == 0) ? bs0 : (sel == 1) ? bs1 : (sel == 2) ? bs2 : bs3;
    const int act = (actmask >> sel) & 1;
    if (VT && sel == vtsel) {
        // transposed write: VT[b][h][dh][t], t-consecutive regs -> ushort4 stores
        const int b = row0 >> 11;
#pragma unroll
        for (int j = 0; j < 4; ++j) {
            const int c2 = (col0 + wc + j * 16 + lm) & 1023;
            const int h  = c2 >> 6;
            const int dh = c2 & 63;
            const float bj = bias[c2];
            u16* vrow = VT + ((size_t)(b * NH + h) * 64 + dh) * (size_t)S_;
#pragma unroll
            for (int i = 0; i < 4; ++i) {
                const int tb = (row0 & 2047) + wr + i * 16 + quad * 4;
                ushort4 o;
                o.x = f2bf(acc[i][j][0] + bj);
                o.y = f2bf(acc[i][j][1] + bj);
                o.z = f2bf(acc[i][j][2] + bj);
                o.w = f2bf(acc[i][j][3] + bj);
                *(ushort4*)&vrow[tb] = o;
            }
        }
    } else {
#pragma unroll
        for (int j = 0; j < 4; ++j) {
            const int colg = col0 + wc + j * 16 + lm;
            const float bj = bias[colg & 1023];
#pragma unroll
            for (int i = 0; i < 4; ++i) {
#pragma unroll
                for (int r = 0; r < 4; ++r) {
                    const int rowg = row0 + wr + i * 16 + quad * 4 + r;
                    float v = acc[i][j][r] + bj;
                    if (act) v = silu_fast(v);
                    outb[(size_t)rowg * ldo + colg] = f2bf(v);
                }
            }
        }
    }
}

// ---------------- 128x64 MFMA GEMM (for N=1024: w0, w2) ----------------
__global__ __launch_bounds__(256) void gemm64(
    const u16* __restrict__ A, int lda, const u16* __restrict__ WT,
    const float* __restrict__ bias,
    const float* __restrict__ res,
    float* __restrict__ outf, int ldo)
{
    __shared__ u16 As[128 * 32];
    __shared__ u16 Bs[64 * 32];
    const int tid  = threadIdx.x;
    const int wave = tid >> 6;
    const int lane = tid & 63;
    const int lm   = lane & 15;
    const int quad = lane >> 4;
    const int row0 = blockIdx.y << 7;
    const int col0 = blockIdx.x << 6;
    const int wr = (wave >> 1) << 6;
    const int wc = (wave & 1) << 5;

    const int srA = wave * 32 + (lane >> 2);
    const int srB = wave * 16 + (lane >> 2);
    const int skp = (lane & 3) << 3;
    const u16* Ag = A  + (size_t)(row0 + srA) * lda + skp;
    const u16* Bg = WT + (size_t)(col0 + srB) * 1024 + skp;
    u16* Asd0 = &As[(wave * 32) * 32];
    u16* Asd1 = &As[(wave * 32 + 16) * 32];
    u16* Bsd  = &Bs[(wave * 16) * 32];

    f32x4 acc[4][2] = {};

    for (int k0 = 0; k0 < 1024; k0 += 32) {
        __syncthreads();
        __builtin_amdgcn_global_load_lds(
            (const __attribute__((address_space(1))) void*)(Ag + k0),
            (__attribute__((address_space(3))) void*)Asd0, 16, 0, 0);
        __builtin_amdgcn_global_load_lds(
            (const __attribute__((address_space(1))) void*)(Ag + (size_t)16 * lda + k0),
            (__attribute__((address_space(3))) void*)Asd1, 16, 0, 0);
        __builtin_amdgcn_global_load_lds(
            (const __attribute__((address_space(1))) void*)(Bg + k0),
            (__attribute__((address_space(3))) void*)Bsd, 16, 0, 0);
        __syncthreads();
        short8 af[4], bf[2];
#pragma unroll
        for (int i = 0; i < 4; ++i)
            af[i] = *(const short8*)&As[(wr + i * 16 + lm) * 32 + quad * 8];
#pragma unroll
        for (int j = 0; j < 2; ++j)
            bf[j] = *(const short8*)&Bs[(wc + j * 16 + lm) * 32 + quad * 8];
#pragma unroll
        for (int i = 0; i < 4; ++i)
#pragma unroll
            for (int j = 0; j < 2; ++j)
                acc[i][j] = __builtin_amdgcn_mfma_f32_16x16x32_bf16(af[i], bf[j], acc[i][j], 0, 0, 0);
    }
#pragma unroll
    for (int j = 0; j < 2; ++j) {
        const int colg = col0 + wc + j * 16 + lm;
        const float bj = bias[colg];
#pragma unroll
        for (int i = 0; i < 4; ++i) {
#pragma unroll
            for (int r = 0; r < 4; ++r) {
                const int rowg = row0 + wr + i * 16 + quad * 4 + r;
                const size_t idx = (size_t)rowg * ldo + colg;
                float v = acc[i][j][r] + bj;
                if (res) v += res[idx];
                outf[idx] = v;
            }
        }
    }
}

// ---------------- MFMA SiLU attention: 32x32 swapped-QK, in-register P ----------
// Wave owns 32 q-rows. st = mfma32x32(K, Q): lane holds S[t=crow(r,hi)][q=lane&31],
// crow = (r&3)+8*(r>>2)+4*hi. silu is lane-local; C->A-frag rearrange is
// 8 cvt_pk_bf16 + 2x2 permlane32_swap per 32x32 subtile (full-rate VALU, no LDS pipe).
// swap(VDST=pk[4m], VSRC=pk[4m+2]): VDST.hi32<->VSRC.lo32 => pk[4m]=A-word0 both
// halves, pk[4m+2]=A-word2. K/V staged XOR-swizzled glds (conflict-free). 40KB LDS.
__global__ __launch_bounds__(256, 4) void attn_mfma(
    const u16* __restrict__ qkvu, const u16* __restrict__ VT,
    const float* __restrict__ pbT, u16* __restrict__ out)
{
    __shared__ u16 Ks[2][64 * 64];
    __shared__ u16 Vs[2][64 * 64];
    __shared__ float pbl[S_];
    const int tid  = threadIdx.x;
    const int wave = tid >> 6;
    const int lane = tid & 63;
    const int l31  = lane & 31;
    const int hi   = lane >> 5;
    const int l7   = lane & 7;
    // grid 512 (16 s-blocks x 16 h x 2 b); XCD chunk swizzle (512%8==0, bijective)
    const int flat = blockIdx.x + (blockIdx.y << 4) + (blockIdx.z << 8);
    const int work = ((flat & 7) << 6) + (flat >> 3);
    const int s0 = (work & 15) << 7;
    const int h  = (work >> 4) & 15;
    const int b  = work >> 8;
    const size_t base = (size_t)b * S_ * LQ + (size_t)h * DH;
    const u16* q  = qkvu + base;
    const u16* kg = qkvu + base + 1024;
    const u16* vt = VT + (size_t)(b * NH + h) * 64 * S_;
    const float* pbh = pbT + (size_t)h * S_;

    for (int i = tid * 4; i < S_; i += 1024)
        *(float4*)&pbl[i] = *(const float4*)&pbh[i];

    // Q B-fragments: col=q=l31, k=dh=16*i + 8*hi + j  (16B contiguous per lane)
    const int qrow = s0 + wave * 32 + l31;
    short8 qf[4];
#pragma unroll
    for (int i = 0; i < 4; ++i)
        qf[i] = *(const short8*)&q[(size_t)qrow * LQ + i * 16 + hi * 8];

    // staging: wave stages rows [16w,16w+16) of the 64-row K (t) and V (dh) tiles
    const int lr  = lane >> 3;
    const int gch = l7 ^ lr;
    const u16* kg0 = kg + (size_t)(16 * wave + lr) * LQ + gch * 8;
    const u16* vg0 = vt + (size_t)(16 * wave + lr) * S_ + gch * 8;

#define GLDS(gp, lp) __builtin_amdgcn_global_load_lds( \
        (const __attribute__((address_space(1))) void*)(gp), \
        (__attribute__((address_space(3))) void*)(lp), 16, 0, 0)

    GLDS(kg0,                     &Ks[0][(16 * wave) * 64]);
    GLDS(kg0 + (size_t)8 * LQ,    &Ks[0][(16 * wave + 8) * 64]);
    GLDS(vg0,                     &Vs[0][(16 * wave) * 64]);
    GLDS(vg0 + (size_t)8 * S_,    &Vs[0][(16 * wave + 8) * 64]);

    f32x16 accO[2] = {};
    __syncthreads();

    for (int t0 = 0; t0 < S_; t0 += 64) {
        const int ib = (t0 >> 6) & 1;
        const int nb = ib ^ 1;
        if (t0 + 64 < S_) {
            const size_t tn = (size_t)(t0 + 64);
            GLDS(kg0 + tn * LQ,             &Ks[nb][(16 * wave) * 64]);
            GLDS(kg0 + (tn + 8) * LQ,       &Ks[nb][(16 * wave + 8) * 64]);
            GLDS(vg0 + tn,                  &Vs[nb][(16 * wave) * 64]);
            GLDS(vg0 + tn + (size_t)8 * S_, &Vs[nb][(16 * wave + 8) * 64]);
        }
#pragma unroll
        for (int half = 0; half < 2; ++half) {
            const int ts = half << 5;
            // ---- QK: A = K rows [ts,ts+32), k = dh ----
            f32x16 st = {};
            __builtin_amdgcn_s_setprio(1);
#pragma unroll
            for (int i = 0; i < 4; ++i) {
                short8 kf = *(const short8*)&Ks[ib][(ts + l31) * 64 + (((2 * i + hi) ^ l7) << 3)];
                st = __builtin_amdgcn_mfma_f32_32x32x16_bf16(kf, qf[i], st, 0, 0, 0);
            }
            __builtin_amdgcn_s_setprio(0);
            // ---- silu + pack: lane-local, t = 8g + 4hi + c ----
            int pk[8];
#pragma unroll
            for (int g = 0; g < 4; ++g) {
                float4 pbv = *(const float4*)&pbl[t0 + ts + 8 * g + 4 * hi];
                float p0 = silu_fast(fmaf(st[4 * g + 0], 0.125f, pbv.x));
                float p1 = silu_fast(fmaf(st[4 * g + 1], 0.125f, pbv.y));
                float p2 = silu_fast(fmaf(st[4 * g + 2], 0.125f, pbv.z));
                float p3 = silu_fast(fmaf(st[4 * g + 3], 0.125f, pbv.w));
                asm("v_cvt_pk_bf16_f32 %0, %1, %2" : "=v"(pk[2 * g])     : "v"(p0), "v"(p1));
                asm("v_cvt_pk_bf16_f32 %0, %1, %2" : "=v"(pk[2 * g + 1]) : "v"(p2), "v"(p3));
            }
            // ---- A-frags via permlane32_swap (VDST=low word, VSRC=high word) ----
#pragma unroll
            for (int m = 0; m < 2; ++m) {
                int w0 = pk[4 * m + 0], w2 = pk[4 * m + 2];
                int w1 = pk[4 * m + 1], w3 = pk[4 * m + 3];
                asm("v_permlane32_swap_b32 %0, %1" : "+v"(w0), "+v"(w2));
                asm("v_permlane32_swap_b32 %0, %1" : "+v"(w1), "+v"(w3));
                union { int4v i; short8 s; } pa;
                pa.i.x = w0; pa.i.y = w1; pa.i.z = w2; pa.i.w = w3;
                __builtin_amdgcn_s_setprio(1);
#pragma unroll
                for (int n = 0; n < 2; ++n) {
                    short8 vf = *(const short8*)&Vs[ib][(32 * n + l31) * 64 +
                        ((((ts >> 3) + 2 * m + hi) ^ l7) << 3)];
                    accO[n] = __builtin_amdgcn_mfma_f32_32x32x16_bf16(pa.s, vf, accO[n], 0, 0, 0);
                }
                __builtin_amdgcn_s_setprio(0);
            }
        }
        __syncthreads();
    }
#undef GLDS
    // epilogue: accO[n] C-layout: row(q-offset)=crow(r,hi), col(dh)=32n+l31
    const int qb = s0 + wave * 32 + 4 * hi;
#pragma unroll
    for (int n = 0; n < 2; ++n)
#pragma unroll
        for (int r = 0; r < 16; ++r) {
            const int qq = qb + (r & 3) + 8 * (r >> 2);
            out[base + (size_t)qq * LQ + 32 * n + l31] = f2bf(accO[n][r]);
        }
}

// ---------------- SwiGLU on QKVU: x1=cols[0,1024), x2=[1024,2048) -> [2048,3072) ----
__global__ __launch_bounds__(256) void swiglu_kernel(u16* __restrict__ qkvu)
{
    const size_t e = ((size_t)blockIdx.x * 256 + threadIdx.x) << 2;
    const size_t r = e >> 10;
    const int    c = (int)(e & 1023);
    ushort4 a = *(const ushort4*)&qkvu[r * LQ + c];
    ushort4 b = *(const ushort4*)&qkvu[r * LQ + 1024 + c];
    ushort4 o;
    o.x = f2bf(silu_fast(bf2f(a.x)) * bf2f(b.x));
    o.y = f2bf(silu_fast(bf2f(a.y)) * bf2f(b.y));
    o.z = f2bf(silu_fast(bf2f(a.z)) * bf2f(b.z));
    o.w = f2bf(silu_fast(bf2f(a.w)) * bf2f(b.w));
    *(ushort4*)&qkvu[r * LQ + 2048 + c] = o;
}

extern "C" void kernel_launch(void* const* d_in, const int* in_sizes, int n_in,
                              void* d_out, int out_size, void* d_ws, size_t ws_size,
                              hipStream_t stream)
{
    const float* x      = (const float*)d_in[0];
    const float* pb     = (const float*)d_in[2];
    const float* wq     = (const float*)d_in[3];
    const float* bq     = (const float*)d_in[4];
    const float* wk     = (const float*)d_in[5];
    const float* bk     = (const float*)d_in[6];
    const float* wv     = (const float*)d_in[7];
    const float* bv     = (const float*)d_in[8];
    const float* wu     = (const float*)d_in[9];
    const float* bu     = (const float*)d_in[10];
    const float* g_ams  = (const float*)d_in[11];
    const float* w0     = (const float*)d_in[12];
    const float* b0     = (const float*)d_in[13];
    const float* w1     = (const float*)d_in[14];
    const float* b1     = (const float*)d_in[15];
    const float* w2     = (const float*)d_in[16];
    const float* b2     = (const float*)d_in[17];
    const float* g_mffn = (const float*)d_in[18];
    float* OUT = (float*)d_out;
    u16*   VT  = (u16*)d_out;              // VT[b][h][64][2048] (8 MB) — dead after attn
    float* pbT = (float*)((u16*)d_out + 4 * (1u << 20));  // 128KB at +8MB — dead after attn

    const size_t MI = 1024 * 1024;
    u16* WS   = (u16*)d_ws;                // 56 MB total
    u16* wT4  = WS;
    u16* w0T  = WS + 4 * MI;
    u16* w2T  = WS + 5 * MI;
    u16* w1T  = WS + 6 * MI;
    u16* A0   = WS + 8 * MI;
    u16* QKVU = WS + 12 * MI;

    dim3 blk(256);

    transpose_all_kernel<<<dim3(16, 16, 8), blk, 0, stream>>>(
        wq, wk, wv, wu, w0, w2, w1, wT4, w0T, w2T, w1T);
    pbt_kernel<<<16, blk, 0, stream>>>(pb, pbT);

    rmsnorm_kernel<<<ROWS, blk, 0, stream>>>(x, nullptr, D, g_ams, nullptr, 0, A0, D);
    gemm128<<<dim3(32, 32), blk, 0, stream>>>(A0, wT4, bq, bk, bv, bu,
                                              QKVU, LQ, 0b1000, VT, 2);
    attn_mfma<<<dim3(16, 16, 2), blk, 0, stream>>>(QKVU, VT, pbT, QKVU);
    rmsnorm_kernel<<<ROWS, blk, 0, stream>>>(nullptr, QKVU, LQ, g_ams, QKVU + 3072, LQ, A0, D);
    gemm64<<<dim3(16, 32), blk, 0, stream>>>(A0, D, w0T, b0, x, OUT, D);
    rmsnorm_kernel<<<ROWS, blk, 0, stream>>>(OUT, nullptr, D, g_mffn, nullptr, 0, A0, D);
    gemm128<<<dim3(16, 32), blk, 0, stream>>>(A0, w1T, b1, b1 + 1024, b1, b1,
                                              QKVU, LQ, 0, nullptr, -1);
    swiglu_kernel<<<ROWS * D / 1024, blk, 0, stream>>>(QKVU);
    gemm64<<<dim3(16, 32), blk, 0, stream>>>(QKVU + 2048, LQ, w2T, b2, OUT, OUT, D);
    (void)ws_size; (void)in_sizes; (void)n_in; (void)out_size;
}